// Round 10
// baseline (259.952 us; speedup 1.0000x reference)
//
#include <hip/hip_runtime.h>

#define B_ 64
#define N_ 196
#define D_ 768
#define H_ 3072
#define M_ (B_*N_)   // 12544
#define NP 256       // padded token count for attn GEMM K / M

typedef int int4v  __attribute__((ext_vector_type(4)));
typedef int int16v __attribute__((ext_vector_type(16)));
typedef signed char i8;

// ---- workspace layout ----
#define WS_MAX 0                 // float[8]: 0 n1w,1 attn,2 g1,3 n2,4 fc1,5 fc2,6 g2
#define WS_W1F 16
#define WS_B1F (16+768)
#define WS_G1F (16+768*2)
#define WS_W2F (16+768*3)
#define WS_B2F (16+768*4)
#define WS_G2F (16+768*5)
#define WS_BA  (16+768*6)        // int[256]
#define WS_BF1 (WS_BA+256)       // int[3072]
#define WS_BF2 (WS_BF1+3072)     // int[768]
// byte offsets. GEMM operands stored CHUNK-MAJOR (CM):
//   [rblk=r/128][kblk=k/64][ksub=(k%64)/16][row=r%128][16B]
// -> staging is a linear 8KB copy; fragment ds_read phases are contiguous.
#define OFF_WA   40960ull                      // CM, 256 rows, K=256 (zero-padded)
#define OFF_FC1  (OFF_WA+65536ull)             // CM, 3072 rows, K=768
#define OFF_FC2  (OFF_FC1+2359296ull)          // CM, 768 rows, K=3072
#define OFF_X2   (OFF_FC2+2359296ull)          // i8[12544][768] row-major
#define OFF_Q3   (OFF_X2+9633792ull)           // CM, 12544 rows, K=768
#define OFF_Q4   (OFF_Q3+9633792ull)           // CM, 12544 rows, K=3072
// q1T (CM, per-batch 768 rows x K=256) and x8 alias the q4 region
#define OFF_Q1T  OFF_Q4                        // 64 x 196608 B
#define OFF_X8   (OFF_Q4+12582912ull)          // i8[12544][768] row-major rint(x/a0)

__device__ __forceinline__ float clamp8(float v){ return fminf(fmaxf(v,-128.f),127.f); }

// async global->LDS, 16B per lane. lds dest = wave-uniform base + lane*16.
__device__ __forceinline__ void async16(const void* g, void* l){
    __builtin_amdgcn_global_load_lds((const __attribute__((address_space(1))) void*)g,
                                     (__attribute__((address_space(3))) void*)l, 16, 0, 0);
}

__global__ void k_init(char* ws, const float* __restrict__ act, float* out_tail){
    int id = blockIdx.x*256 + threadIdx.x;
    if (blockIdx.x == 0){
        float* f = (float*)ws;
        if (threadIdx.x < 8) f[WS_MAX+threadIdx.x] = 0.f;
        if (threadIdx.x == 8) *out_tail = act[7];
    }
    if (id < 4096){ int4v z = {0,0,0,0}; ((int4v*)(ws+OFF_WA))[id] = z; }
}

__global__ void k_maxabs(const float* __restrict__ p0, const float* __restrict__ p1,
                         const float* __restrict__ p2, const float* __restrict__ p3,
                         const float* __restrict__ p4, const float* __restrict__ p5,
                         const float* __restrict__ p6, float* wsmax){
    const float* ps[7] = {p0,p1,p2,p3,p4,p5,p6};
    const int    n4s[7] = {192, 9604, 192, 192, 589824, 589824, 192};
    int tid = blockIdx.y;
    const float4* p = (const float4*)ps[tid]; int n4 = n4s[tid];
    float m = 0.f;
    for (int i = blockIdx.x*blockDim.x + threadIdx.x; i < n4; i += gridDim.x*blockDim.x){
        float4 v = p[i];
        m = fmaxf(m, fmaxf(fmaxf(fabsf(v.x),fabsf(v.y)), fmaxf(fabsf(v.z),fabsf(v.w))));
    }
    #pragma unroll
    for (int off = 32; off; off >>= 1) m = fmaxf(m, __shfl_down(m, off, 64));
    __shared__ float red[4];
    int lane = threadIdx.x & 63, wv = threadIdx.x >> 6;
    if (lane == 0) red[wv] = m;
    __syncthreads();
    if (threadIdx.x == 0){
        float mm = red[0];
        for (int w = 1; w < (int)blockDim.x/64; w++) mm = fmaxf(mm, red[w]);
        atomicMax((unsigned*)&wsmax[tid], __float_as_uint(mm));
    }
}

// chunk-major offset for row o, k; KC = K/64
__device__ __forceinline__ size_t cm_off(int o, int k, int KC){
    return (((size_t)(o>>7)*KC + (k>>6))<<13) + (((k>>4)&3)<<11) + ((o&127)<<4) + (k&15);
}

__global__ void k_qweights(const float* __restrict__ n1w, const float* __restrict__ n1b,
                           const float* __restrict__ aw,  const float* __restrict__ ab,
                           const float* __restrict__ g1w, const float* __restrict__ n2w,
                           const float* __restrict__ n2b, const float* __restrict__ f1w,
                           const float* __restrict__ f1b, const float* __restrict__ f2w,
                           const float* __restrict__ f2b, const float* __restrict__ g2w,
                           const float* __restrict__ act, char* ws){
    float* fws = (float*)ws;
    int*   iws = (int*)ws;
    const float* mx = fws + WS_MAX;
    long i = (long)blockIdx.x*blockDim.x + threadIdx.x;
    const long F4 = 589824;
    if (i < F4){ float sf = mx[4]/127.0f;
        float4 v = ((const float4*)f1w)[i];
        int o = (int)(i/192), kb = (int)(i%192)*4;
        unsigned b0 = (unsigned)(unsigned char)(i8)(int)fminf(fmaxf(rintf(v.x/sf),-128.f),127.f);
        unsigned b1 = (unsigned)(unsigned char)(i8)(int)fminf(fmaxf(rintf(v.y/sf),-128.f),127.f);
        unsigned b2 = (unsigned)(unsigned char)(i8)(int)fminf(fmaxf(rintf(v.z/sf),-128.f),127.f);
        unsigned b3 = (unsigned)(unsigned char)(i8)(int)fminf(fmaxf(rintf(v.w/sf),-128.f),127.f);
        *(unsigned*)(ws + OFF_FC1 + cm_off(o, kb, 12)) = b0 | (b1<<8) | (b2<<16) | (b3<<24);
        return; }
    i -= F4;
    if (i < F4){ float sf = mx[5]/127.0f;
        float4 v = ((const float4*)f2w)[i];
        int o = (int)(i/768), kb = (int)(i%768)*4;
        unsigned b0 = (unsigned)(unsigned char)(i8)(int)fminf(fmaxf(rintf(v.x/sf),-128.f),127.f);
        unsigned b1 = (unsigned)(unsigned char)(i8)(int)fminf(fmaxf(rintf(v.y/sf),-128.f),127.f);
        unsigned b2 = (unsigned)(unsigned char)(i8)(int)fminf(fmaxf(rintf(v.z/sf),-128.f),127.f);
        unsigned b3 = (unsigned)(unsigned char)(i8)(int)fminf(fmaxf(rintf(v.w/sf),-128.f),127.f);
        *(unsigned*)(ws + OFF_FC2 + cm_off(o, kb, 48)) = b0 | (b1<<8) | (b2<<16) | (b3<<24);
        return; }
    i -= F4;
    if (i < 38416){ float sf = mx[1]/127.0f;
        int o = (int)(i/196), k = (int)(i%196);
        ((i8*)(ws+OFF_WA))[cm_off(o, k, 4)] =
            (i8)(int)fminf(fmaxf(rintf(aw[i]/sf),-128.f),127.f); return; }
    i -= 38416;
    if (i < 768){ float sf = mx[0]/127.0f; fws[WS_W1F+i] = rintf(n1w[i]/sf); return; }
    i -= 768;
    if (i < 768){ float sf = mx[0]/127.0f; fws[WS_B1F+i] = rintf(n1b[i]/(act[0]*sf)); return; }
    i -= 768;
    if (i < 768){ float sf = mx[2]/127.0f; fws[WS_G1F+i] = rintf(g1w[i]/sf); return; }
    i -= 768;
    if (i < 768){ float sf = mx[3]/127.0f; fws[WS_W2F+i] = rintf(n2w[i]/sf); return; }
    i -= 768;
    if (i < 768){ float sf = mx[3]/127.0f; fws[WS_B2F+i] = rintf(n2b[i]/(act[3]*sf)); return; }
    i -= 768;
    if (i < 768){ float sf = mx[6]/127.0f; fws[WS_G2F+i] = rintf(g2w[i]/sf); return; }
    i -= 768;
    if (i < 196){ float sf = mx[1]/127.0f; iws[WS_BA+i] = (int)rintf(ab[i]/(act[1]*sf)); return; }
    i -= 196;
    if (i < 3072){ float sf = mx[4]/127.0f; iws[WS_BF1+i] = (int)rintf(f1b[i]/(act[4]*sf)); return; }
    i -= 3072;
    if (i < 768){ float sf = mx[5]/127.0f; iws[WS_BF2+i] = (int)rintf(f2b[i]/(act[5]*sf)); return; }
}

// norm1 + quant_act1 -> q1T CM (per-batch, rows=d 768, K=n 256) + x8 row-major.
__global__ __launch_bounds__(256) void k_stage1(const float* __restrict__ x,
                                                const char* __restrict__ wsc,
                                                char* __restrict__ ws,
                                                const float* __restrict__ act){
    __shared__ i8 T[64][68];
    const float* fws = (const float*)wsc;
    int b = blockIdx.z, n0 = blockIdx.y*64, d0 = blockIdx.x*64;
    int t = threadIdx.x;
    float a0 = act[0];
    float w1sf = fws[WS_MAX+0]/127.0f;
    float r1 = (a0*w1sf)/act[1];
    int dl = (t & 15) * 4;
    int d  = d0 + dl;
    float4 wv = *(const float4*)(fws + WS_W1F + d);
    float4 bv = *(const float4*)(fws + WS_B1F + d);
    i8* x8 = (i8*)(ws + OFF_X8);
    #pragma unroll
    for (int pass = 0; pass < 4; pass++){
        int nl = (t >> 4) + pass*16;
        int n  = n0 + nl;
        i8 q[4] = {0,0,0,0};
        if (n < 196){
            float4 xv = *(const float4*)(x + ((size_t)b*196 + n)*768 + d);
            float i0 = rintf(xv.x/a0), i1 = rintf(xv.y/a0);
            float i2 = rintf(xv.z/a0), i3 = rintf(xv.w/a0);
            *(char4*)(x8 + ((size_t)b*196 + n)*768 + d) =
                make_char4((i8)(int)i0,(i8)(int)i1,(i8)(int)i2,(i8)(int)i3);
            float o0 = rintf(i0*wv.x + bv.x);
            float o1 = rintf(i1*wv.y + bv.y);
            float o2 = rintf(i2*wv.z + bv.z);
            float o3 = rintf(i3*wv.w + bv.w);
            q[0] = (i8)(int)clamp8(rintf(o0*r1));
            q[1] = (i8)(int)clamp8(rintf(o1*r1));
            q[2] = (i8)(int)clamp8(rintf(o2*r1));
            q[3] = (i8)(int)clamp8(rintf(o3*r1));
        }
        T[dl+0][nl] = q[0]; T[dl+1][nl] = q[1];
        T[dl+2][nl] = q[2]; T[dl+3][nl] = q[3];
    }
    __syncthreads();
    i8* q1T = (i8*)(ws + OFF_Q1T) + (size_t)b*196608;
    #pragma unroll
    for (int e = 0; e < 4; e++){
        int id = t + e*256;
        int row = id >> 4, c = (id & 15) * 4;   // d-row local, n-col local
        int dd = d0 + row;
        int v = *(const int*)&T[row][c];
        size_t dst = (((size_t)(dd>>7)*4 + blockIdx.y)<<13) + ((size_t)(c>>4)<<11)
                     + ((dd&127)<<4) + (c&15);
        *(int*)(q1T + dst) = v;
    }
}

// CM double-buffered int8 GEMM, 256 threads: 128x128 tile, wave tile 64x64,
// 16x16x64 fragments. Used by attn (only 4 iters; pipeline depth not worth it).
__device__ __forceinline__ void gemm_cm_256(const i8* __restrict__ gA, const i8* __restrict__ gB,
                                            int iters, int4v acc[4][4], i8* As, i8* Bs, int t){
    int lane = t & 63;
    int wm = (t>>6)&1, wn = t>>7;
    int lo = t*16;
    async16(gA + lo,        As + lo);
    async16(gA + 4096 + lo, As + 4096 + lo);
    async16(gB + lo,        Bs + lo);
    async16(gB + 4096 + lo, Bs + 4096 + lo);
    int arow = (lane>>4)*2048 + (wm*64 + (lane&15))*16;
    int brow = (lane>>4)*2048 + (wn*64 + (lane&15))*16;
    for (int i = 0; i < iters; i++){
        __syncthreads();
        if (i+1 < iters){
            int nb = ((i+1)&1) << 13;
            size_t kb = (size_t)(i+1) << 13;
            async16(gA + kb + lo,        As + nb + lo);
            async16(gA + kb + 4096 + lo, As + nb + 4096 + lo);
            async16(gB + kb + lo,        Bs + nb + lo);
            async16(gB + kb + 4096 + lo, Bs + nb + 4096 + lo);
        }
        int cb = (i&1) << 13;
        int4v a[4], bb[4];
        #pragma unroll
        for (int mt = 0; mt < 4; mt++)
            a[mt] = *(const int4v*)(As + cb + arow + mt*256);
        #pragma unroll
        for (int nt = 0; nt < 4; nt++)
            bb[nt] = *(const int4v*)(Bs + cb + brow + nt*256);
        #pragma unroll
        for (int mt = 0; mt < 4; mt++)
            #pragma unroll
            for (int nt = 0; nt < 4; nt++)
                acc[mt][nt] = __builtin_amdgcn_mfma_i32_16x16x64_i8(a[mt], bb[nt], acc[mt][nt], 0,0,0);
    }
}

// attn (4 waves): CM operands; epilogue -> x2 row-major, q3 CM. (R4 version.)
__global__ __launch_bounds__(256) void k_attn(const char* __restrict__ ws,
                                              const float* __restrict__ act){
    __shared__ char smem[32768];
    const float* fws = (const float*)ws;
    const int*   iws = (const int*)ws;
    int b = blockIdx.z;
    int m0 = blockIdx.x*128, n0 = blockIdx.y*128;
    const i8* gA = (const i8*)(ws + OFF_WA)  + ((size_t)(m0>>7))*32768;
    const i8* gB = (const i8*)(ws + OFF_Q1T) + (size_t)b*196608 + ((size_t)(n0>>7))*32768;
    const i8* x8 = (const i8*)(ws + OFF_X8);
    i8* x2  = (i8*)(ws + OFF_X2);
    i8* q3  = (i8*)(ws + OFF_Q3);
    int t = threadIdx.x, lane = t & 63;
    int wm = (t>>6)&1, wn = t>>7;
    int4v acc[4][4]; int4v zz = {0,0,0,0};
    #pragma unroll
    for (int mt=0;mt<4;mt++) for (int nt=0;nt<4;nt++) acc[mt][nt] = zz;
    gemm_cm_256(gA, gB, 4, acc, (i8*)smem, (i8*)smem+16384, t);

    float a1=act[1], a2=act[2], a3=act[3], a4=act[4];
    float wasf = fws[WS_MAX+1]/127.0f; float r2  = (a1*wasf)/a2;
    float g1sf = fws[WS_MAX+2]/127.0f; float r3a = (a2*g1sf)/a3; float r3b = act[0]/a3;
    float w2sf = fws[WS_MAX+3]/127.0f; float r4  = (a3*w2sf)/a4;
    float g1v[4], w2v[4], b2v[4];
    #pragma unroll
    for (int nt=0;nt<4;nt++){
        int d = n0 + wn*64 + nt*16 + (lane&15);
        g1v[nt] = fws[WS_G1F + d]; w2v[nt] = fws[WS_W2F + d]; b2v[nt] = fws[WS_B2F + d];
    }
    __syncthreads();
    i8* Xs = (i8*)smem;
    i8* Qs = (i8*)smem + 16384;
    #pragma unroll
    for (int mt=0;mt<4;mt++){
        #pragma unroll
        for (int r=0;r<4;r++){
            int ml = wm*64 + mt*16 + (lane>>4)*4 + r;
            int o  = m0 + ml;
            int ba = iws[WS_BA + o];
            #pragma unroll
            for (int nt=0;nt<4;nt++){
                int nl = wn*64 + nt*16 + (lane&15);
                int d  = n0 + nl;
                float s2 = (float)(acc[mt][nt][r] + ba);
                float q2 = clamp8(rintf(s2*r2));
                float o3v = q2*g1v[nt];
                float idi = (o < 196) ? (float)x8[((size_t)b*196 + o)*768 + d] : 0.f;
                float tt = rintf(o3v*r3a) + rintf(idi*r3b);
                tt = clamp8(tt);
                float o4 = tt*w2v[nt] + b2v[nt];
                float qr = clamp8(rintf(o4*r4));
                Xs[ml*128 + nl] = (i8)(int)tt;
                Qs[ml*128 + nl] = (i8)(int)qr;
            }
        }
    }
    __syncthreads();
    #pragma unroll
    for (int e=0;e<4;e++){
        int id = t + e*256;
        int row = id>>3, c = id&7;
        int o = m0 + row;
        if (o < 196){
            int rg = b*196 + o;
            size_t g = (size_t)rg*768 + n0 + c*16;
            *(int4v*)(x2 + g) = *(const int4v*)(Xs + row*128 + c*16);
            size_t dst = (((size_t)(rg>>7)*12 + (n0>>6) + (c>>2))<<13)
                         + ((size_t)(c&3)<<11) + ((rg&127)<<4);
            *(int4v*)(q3 + dst) = *(const int4v*)(Qs + row*128 + c*16);
        }
    }
}

// fc1: q3(CM) x fc1(CM) -> relu -> quant -> q4(CM).
// 256x128 tile, 4 waves, wave tile 128x64 (4mt x 2nt), BK=64,
// double-buffered 2x24KB LDS, stage-after-barrier + vmcnt(0) cadence.
// (R9 version — proven: fc1 dropped out of the top-5.)
__global__ __launch_bounds__(256,2) void k_fc1(const char* __restrict__ ws, const float* __restrict__ act){
    __shared__ char smem[49152];
    const float* fws = (const float*)ws;
    const int*   iws = (const int*)ws;
    int orig = blockIdx.x;
    int wg = (orig & 7) * 147 + (orig >> 3);
    int bx = wg / 24;          // 256-row block 0..48
    int by = wg % 24;          // 128-col block 0..23
    int n0 = by*128;
    const i8* gA = (const i8*)(ws+OFF_Q3)  + (size_t)bx*2*98304;   // 98304 = 12 kblk * 8KB
    const i8* gB = (const i8*)(ws+OFF_FC1) + (size_t)by*98304;
    const int* bias = iws + WS_BF1;
    i8* q4 = (i8*)(ws+OFF_Q4);
    int t = threadIdx.x, lane = t & 63;
    int wm = (t>>6)&1, wn = t>>7;
    int lo = t*16;
    int16v acc[4][2];
    int16v zz = {0,0,0,0,0,0,0,0,0,0,0,0,0,0,0,0};
    #pragma unroll
    for (int mt=0;mt<4;mt++) for (int nt=0;nt<2;nt++) acc[mt][nt] = zz;
    auto stage = [&](int s, int buf){
        size_t kb = (size_t)s << 13;
        i8* L = (i8*)smem + buf*24576;
        async16(gA + kb + lo,                 L + lo);
        async16(gA + kb + 4096 + lo,          L + 4096 + lo);
        async16(gA + 98304 + kb + lo,         L + 8192 + lo);
        async16(gA + 98304 + kb + 4096 + lo,  L + 12288 + lo);
        async16(gB + kb + lo,                 L + 16384 + lo);
        async16(gB + kb + 4096 + lo,          L + 20480 + lo);
    };
    stage(0, 0);
    int arow = wm*8192  + (lane>>5)*2048 + (lane&31)*16;             // + kk*4096 + mt*512
    int brow = 16384 + (lane>>5)*2048 + (wn*64 + (lane&31))*16;      // + kk*4096 + nt*512
    for (int i = 0; i < 12; i++){
        asm volatile("s_waitcnt vmcnt(0)" ::: "memory");
        __builtin_amdgcn_s_barrier();
        __builtin_amdgcn_sched_barrier(0);
        if (i+1 < 12) stage(i+1, (i+1)&1);
        const i8* L = (const i8*)smem + (i&1)*24576;
        #pragma unroll
        for (int kk = 0; kk < 2; kk++){
            int4v a[4], bb[2];
            #pragma unroll
            for (int mt = 0; mt < 4; mt++)
                a[mt] = *(const int4v*)(L + kk*4096 + arow + mt*512);
            #pragma unroll
            for (int nt = 0; nt < 2; nt++)
                bb[nt] = *(const int4v*)(L + kk*4096 + brow + nt*512);
            #pragma unroll
            for (int mt = 0; mt < 4; mt++)
                #pragma unroll
                for (int nt = 0; nt < 2; nt++)
                    acc[mt][nt] = __builtin_amdgcn_mfma_i32_32x32x32_i8(a[mt], bb[nt], acc[mt][nt], 0,0,0);
        }
    }
    float wsf = fws[WS_MAX+4]/127.0f;
    float r5 = (act[4]*wsf)/act[5];
    int bcol[2];
    #pragma unroll
    for (int nt=0;nt<2;nt++) bcol[nt] = bias[n0 + wn*64 + nt*32 + (lane&31)];
    __syncthreads();           // all waves done reading LDS before reuse as Cs
    i8* Cs = (i8*)smem;        // 256x128 = 32KB
    #pragma unroll
    for (int mt=0;mt<4;mt++){
        #pragma unroll
        for (int nt=0;nt<2;nt++){
            int nl = wn*64 + nt*32 + (lane&31);
            #pragma unroll
            for (int r=0;r<16;r++){
                int s = acc[mt][nt][r] + bcol[nt];
                if (s < 0) s = 0;
                float q = clamp8(rintf((float)s * r5));
                // 32x32 C/D: col=lane&31, row=(r&3)+8*(r>>2)+4*(lane>>5)
                int ml = wm*128 + mt*32 + 4*(lane>>5) + (r&3) + 8*(r>>2);
                Cs[ml*128 + nl] = (i8)(int)q;
            }
        }
    }
    __syncthreads();
    #pragma unroll
    for (int e=0;e<8;e++){
        int id = t + e*256;
        int row = id>>3, c = id&7;      // row 0..255, c 0..7
        size_t dst = (((size_t)(bx*2 + (row>>7))*48 + (n0>>6) + (c>>2))<<13)
                     + ((size_t)(c&3)<<11) + ((size_t)(row&127)<<4);
        *(int4v*)(q4 + dst) = *(const int4v*)(Cs + row*128 + c*16);
    }
}

// fc2: q4(CM) x fc2(CM) -> quant -> gamma2 -> +identity -> final quant -> fp32.
// NEW: fc1's proven big-tile structure ported: 256x128 tile, 4 waves, wave
// tile 128x64 (4mt x 2nt), BK=64, dbuf 2x24KB, stage-after-barrier+vmcnt(0).
// Grid 294 (49x6) all co-resident at 2 blocks/CU. Epilogue writes fp32 out
// directly from acc (no LDS staging needed). bx-major wg + m204 bijective
// XCD remap (294 = 6*37 + 2*36): the 786KB A-panel's 6 sharers are
// consecutive wgids on one XCD -> L2-resident.
__global__ __launch_bounds__(256,2) void k_fc2(const char* __restrict__ ws, const float* __restrict__ act,
                                               float* __restrict__ out){
    __shared__ char smem[49152];
    const float* fws = (const float*)ws;
    const int*   iws = (const int*)ws;
    int orig = blockIdx.x;
    int xcd = orig & 7, lid = orig >> 3;
    int wg = (xcd < 6 ? xcd*37 : 222 + (xcd-6)*36) + lid;
    int bx = wg / 6;           // 256-row block 0..48
    int by = wg % 6;           // 128-col block 0..5
    int m0 = bx*256, n0 = by*128;
    const i8* gA = (const i8*)(ws+OFF_Q4)  + (size_t)bx*2*393216;  // 393216 = 48 kblk * 8KB
    const i8* gB = (const i8*)(ws+OFF_FC2) + (size_t)by*393216;
    const int* bias = iws + WS_BF2;
    const float* g2f = fws + WS_G2F;
    const i8* x2 = (const i8*)(ws+OFF_X2);
    int t = threadIdx.x, lane = t & 63;
    int wm = (t>>6)&1, wn = t>>7;
    int lo = t*16;
    int16v acc[4][2];
    int16v zz = {0,0,0,0,0,0,0,0,0,0,0,0,0,0,0,0};
    #pragma unroll
    for (int mt=0;mt<4;mt++) for (int nt=0;nt<2;nt++) acc[mt][nt] = zz;
    auto stage = [&](int s, int buf){
        size_t kb = (size_t)s << 13;
        i8* L = (i8*)smem + buf*24576;
        async16(gA + kb + lo,                  L + lo);
        async16(gA + kb + 4096 + lo,           L + 4096 + lo);
        async16(gA + 393216 + kb + lo,         L + 8192 + lo);
        async16(gA + 393216 + kb + 4096 + lo,  L + 12288 + lo);
        async16(gB + kb + lo,                  L + 16384 + lo);
        async16(gB + kb + 4096 + lo,           L + 20480 + lo);
    };
    stage(0, 0);
    int arow = wm*8192  + (lane>>5)*2048 + (lane&31)*16;             // + kk*4096 + mt*512
    int brow = 16384 + (lane>>5)*2048 + (wn*64 + (lane&31))*16;      // + kk*4096 + nt*512
    for (int i = 0; i < 48; i++){
        asm volatile("s_waitcnt vmcnt(0)" ::: "memory");
        __builtin_amdgcn_s_barrier();
        __builtin_amdgcn_sched_barrier(0);
        if (i+1 < 48) stage(i+1, (i+1)&1);
        const i8* L = (const i8*)smem + (i&1)*24576;
        #pragma unroll
        for (int kk = 0; kk < 2; kk++){
            int4v a[4], bb[2];
            #pragma unroll
            for (int mt = 0; mt < 4; mt++)
                a[mt] = *(const int4v*)(L + kk*4096 + arow + mt*512);
            #pragma unroll
            for (int nt = 0; nt < 2; nt++)
                bb[nt] = *(const int4v*)(L + kk*4096 + brow + nt*512);
            #pragma unroll
            for (int mt = 0; mt < 4; mt++)
                #pragma unroll
                for (int nt = 0; nt < 2; nt++)
                    acc[mt][nt] = __builtin_amdgcn_mfma_i32_32x32x32_i8(a[mt], bb[nt], acc[mt][nt], 0,0,0);
        }
    }
    float a3=act[3], a5=act[5], a6=act[6], a7=act[7];
    float wsf  = fws[WS_MAX+5]/127.0f; float r6  = (a5*wsf)/a6;
    float g2sf = fws[WS_MAX+6]/127.0f; float r7a = (a6*g2sf)/a7; float r7b = a3/a7;
    int bcol[2]; float g2v[2];
    #pragma unroll
    for (int nt=0;nt<2;nt++){
        int nc = n0 + wn*64 + nt*32 + (lane&31);
        bcol[nt] = bias[nc]; g2v[nt] = g2f[nc];
    }
    #pragma unroll
    for (int mt=0;mt<4;mt++){
        #pragma unroll
        for (int nt=0;nt<2;nt++){
            int nc = n0 + wn*64 + nt*32 + (lane&31);
            #pragma unroll
            for (int r=0;r<16;r++){
                // 32x32 C/D: col=lane&31, row=(r&3)+8*(r>>2)+4*(lane>>5)
                int ml = wm*128 + mt*32 + 4*(lane>>5) + (r&3) + 8*(r>>2);
                size_t gi = (size_t)(m0+ml)*768 + nc;
                int s = acc[mt][nt][r] + bcol[nt];
                float q6 = clamp8(rintf((float)s*r6));
                float o7 = q6*g2v[nt];
                float idi = (float)x2[gi];
                float tt = rintf(o7*r7a) + rintf(idi*r7b);
                tt = clamp8(tt);
                out[gi] = tt*a7;
            }
        }
    }
}

extern "C" void kernel_launch(void* const* d_in, const int* in_sizes, int n_in,
                              void* d_out, int out_size, void* d_ws, size_t ws_size,
                              hipStream_t stream){
    const float* x   = (const float*)d_in[0];
    const float* n1w = (const float*)d_in[1];
    const float* n1b = (const float*)d_in[2];
    const float* aw  = (const float*)d_in[3];
    const float* ab  = (const float*)d_in[4];
    const float* g1w = (const float*)d_in[5];
    const float* n2w = (const float*)d_in[6];
    const float* n2b = (const float*)d_in[7];
    const float* f1w = (const float*)d_in[8];
    const float* f1b = (const float*)d_in[9];
    const float* f2w = (const float*)d_in[10];
    const float* f2b = (const float*)d_in[11];
    const float* g2w = (const float*)d_in[12];
    const float* act = (const float*)d_in[13];
    char* ws = (char*)d_ws;
    float* out = (float*)d_out;

    k_init<<<16,256,0,stream>>>(ws, act, out + (size_t)B_*N_*D_);
    k_maxabs<<<dim3(120,7),256,0,stream>>>(n1w, aw, g1w, n2w, f1w, f2w, g2w, (float*)ws);
    long qwThreads = 2L*589824 + 38416 + 768L*6 + 196 + 3072 + 768;
    k_qweights<<<(int)((qwThreads+255)/256),256,0,stream>>>(n1w,n1b,aw,ab,g1w,n2w,n2b,
                                                            f1w,f1b,f2w,f2b,g2w,act,ws);
    k_stage1<<<dim3(12,4,64),256,0,stream>>>(x, ws, ws, act);
    k_attn<<<dim3(2,6,64),256,0,stream>>>(ws, act);
    k_fc1<<<1176,256,0,stream>>>(ws, act);
    k_fc2<<<294,256,0,stream>>>(ws, act, out);
}

// Round 11
// 257.922 us; speedup vs baseline: 1.0079x; 1.0079x over previous
//
#include <hip/hip_runtime.h>

#define B_ 64
#define N_ 196
#define D_ 768
#define H_ 3072
#define M_ (B_*N_)   // 12544
#define NP 256       // padded token count for attn GEMM K / M

typedef int int4v  __attribute__((ext_vector_type(4)));
typedef int int16v __attribute__((ext_vector_type(16)));
typedef signed char i8;

// ---- workspace layout ----
#define WS_MAX 0                 // float[8]: 0 n1w,1 attn,2 g1,3 n2,4 fc1,5 fc2,6 g2
#define WS_W1F 16
#define WS_B1F (16+768)
#define WS_G1F (16+768*2)
#define WS_W2F (16+768*3)
#define WS_B2F (16+768*4)
#define WS_G2F (16+768*5)
#define WS_BA  (16+768*6)        // int[256]
#define WS_BF1 (WS_BA+256)       // int[3072]
#define WS_BF2 (WS_BF1+3072)     // int[768]
// byte offsets. GEMM operands stored CHUNK-MAJOR (CM):
//   [rblk=r/128][kblk=k/64][ksub=(k%64)/16][row=r%128][16B]
// -> staging is a linear 8KB copy; fragment ds_read phases are contiguous.
#define OFF_WA   40960ull                      // CM, 256 rows, K=256 (zero-padded)
#define OFF_FC1  (OFF_WA+65536ull)             // CM, 3072 rows, K=768
#define OFF_FC2  (OFF_FC1+2359296ull)          // CM, 768 rows, K=3072
#define OFF_X2   (OFF_FC2+2359296ull)          // i8[12544][768] row-major
#define OFF_Q3   (OFF_X2+9633792ull)           // CM, 12544 rows, K=768
#define OFF_Q4   (OFF_Q3+9633792ull)           // CM, 12544 rows, K=3072
// q1T (CM, per-batch 768 rows x K=256) and x8 alias the q4 region
#define OFF_Q1T  OFF_Q4                        // 64 x 196608 B
#define OFF_X8   (OFF_Q4+12582912ull)          // i8[12544][768] row-major rint(x/a0)

__device__ __forceinline__ float clamp8(float v){ return fminf(fmaxf(v,-128.f),127.f); }

// async global->LDS, 16B per lane. lds dest = wave-uniform base + lane*16.
__device__ __forceinline__ void async16(const void* g, void* l){
    __builtin_amdgcn_global_load_lds((const __attribute__((address_space(1))) void*)g,
                                     (__attribute__((address_space(3))) void*)l, 16, 0, 0);
}

__global__ void k_init(char* ws, const float* __restrict__ act, float* out_tail){
    int id = blockIdx.x*256 + threadIdx.x;
    if (blockIdx.x == 0){
        float* f = (float*)ws;
        if (threadIdx.x < 8) f[WS_MAX+threadIdx.x] = 0.f;
        if (threadIdx.x == 8) *out_tail = act[7];
    }
    if (id < 4096){ int4v z = {0,0,0,0}; ((int4v*)(ws+OFF_WA))[id] = z; }
}

__global__ void k_maxabs(const float* __restrict__ p0, const float* __restrict__ p1,
                         const float* __restrict__ p2, const float* __restrict__ p3,
                         const float* __restrict__ p4, const float* __restrict__ p5,
                         const float* __restrict__ p6, float* wsmax){
    const float* ps[7] = {p0,p1,p2,p3,p4,p5,p6};
    const int    n4s[7] = {192, 9604, 192, 192, 589824, 589824, 192};
    int tid = blockIdx.y;
    const float4* p = (const float4*)ps[tid]; int n4 = n4s[tid];
    float m = 0.f;
    for (int i = blockIdx.x*blockDim.x + threadIdx.x; i < n4; i += gridDim.x*blockDim.x){
        float4 v = p[i];
        m = fmaxf(m, fmaxf(fmaxf(fabsf(v.x),fabsf(v.y)), fmaxf(fabsf(v.z),fabsf(v.w))));
    }
    #pragma unroll
    for (int off = 32; off; off >>= 1) m = fmaxf(m, __shfl_down(m, off, 64));
    __shared__ float red[4];
    int lane = threadIdx.x & 63, wv = threadIdx.x >> 6;
    if (lane == 0) red[wv] = m;
    __syncthreads();
    if (threadIdx.x == 0){
        float mm = red[0];
        for (int w = 1; w < (int)blockDim.x/64; w++) mm = fmaxf(mm, red[w]);
        atomicMax((unsigned*)&wsmax[tid], __float_as_uint(mm));
    }
}

// chunk-major offset for row o, k; KC = K/64
__device__ __forceinline__ size_t cm_off(int o, int k, int KC){
    return (((size_t)(o>>7)*KC + (k>>6))<<13) + (((k>>4)&3)<<11) + ((o&127)<<4) + (k&15);
}

__global__ void k_qweights(const float* __restrict__ n1w, const float* __restrict__ n1b,
                           const float* __restrict__ aw,  const float* __restrict__ ab,
                           const float* __restrict__ g1w, const float* __restrict__ n2w,
                           const float* __restrict__ n2b, const float* __restrict__ f1w,
                           const float* __restrict__ f1b, const float* __restrict__ f2w,
                           const float* __restrict__ f2b, const float* __restrict__ g2w,
                           const float* __restrict__ act, char* ws){
    float* fws = (float*)ws;
    int*   iws = (int*)ws;
    const float* mx = fws + WS_MAX;
    long i = (long)blockIdx.x*blockDim.x + threadIdx.x;
    const long F4 = 589824;
    if (i < F4){ float sf = mx[4]/127.0f;
        float4 v = ((const float4*)f1w)[i];
        int o = (int)(i/192), kb = (int)(i%192)*4;
        unsigned b0 = (unsigned)(unsigned char)(i8)(int)fminf(fmaxf(rintf(v.x/sf),-128.f),127.f);
        unsigned b1 = (unsigned)(unsigned char)(i8)(int)fminf(fmaxf(rintf(v.y/sf),-128.f),127.f);
        unsigned b2 = (unsigned)(unsigned char)(i8)(int)fminf(fmaxf(rintf(v.z/sf),-128.f),127.f);
        unsigned b3 = (unsigned)(unsigned char)(i8)(int)fminf(fmaxf(rintf(v.w/sf),-128.f),127.f);
        *(unsigned*)(ws + OFF_FC1 + cm_off(o, kb, 12)) = b0 | (b1<<8) | (b2<<16) | (b3<<24);
        return; }
    i -= F4;
    if (i < F4){ float sf = mx[5]/127.0f;
        float4 v = ((const float4*)f2w)[i];
        int o = (int)(i/768), kb = (int)(i%768)*4;
        unsigned b0 = (unsigned)(unsigned char)(i8)(int)fminf(fmaxf(rintf(v.x/sf),-128.f),127.f);
        unsigned b1 = (unsigned)(unsigned char)(i8)(int)fminf(fmaxf(rintf(v.y/sf),-128.f),127.f);
        unsigned b2 = (unsigned)(unsigned char)(i8)(int)fminf(fmaxf(rintf(v.z/sf),-128.f),127.f);
        unsigned b3 = (unsigned)(unsigned char)(i8)(int)fminf(fmaxf(rintf(v.w/sf),-128.f),127.f);
        *(unsigned*)(ws + OFF_FC2 + cm_off(o, kb, 48)) = b0 | (b1<<8) | (b2<<16) | (b3<<24);
        return; }
    i -= F4;
    if (i < 38416){ float sf = mx[1]/127.0f;
        int o = (int)(i/196), k = (int)(i%196);
        ((i8*)(ws+OFF_WA))[cm_off(o, k, 4)] =
            (i8)(int)fminf(fmaxf(rintf(aw[i]/sf),-128.f),127.f); return; }
    i -= 38416;
    if (i < 768){ float sf = mx[0]/127.0f; fws[WS_W1F+i] = rintf(n1w[i]/sf); return; }
    i -= 768;
    if (i < 768){ float sf = mx[0]/127.0f; fws[WS_B1F+i] = rintf(n1b[i]/(act[0]*sf)); return; }
    i -= 768;
    if (i < 768){ float sf = mx[2]/127.0f; fws[WS_G1F+i] = rintf(g1w[i]/sf); return; }
    i -= 768;
    if (i < 768){ float sf = mx[3]/127.0f; fws[WS_W2F+i] = rintf(n2w[i]/sf); return; }
    i -= 768;
    if (i < 768){ float sf = mx[3]/127.0f; fws[WS_B2F+i] = rintf(n2b[i]/(act[3]*sf)); return; }
    i -= 768;
    if (i < 768){ float sf = mx[6]/127.0f; fws[WS_G2F+i] = rintf(g2w[i]/sf); return; }
    i -= 768;
    if (i < 196){ float sf = mx[1]/127.0f; iws[WS_BA+i] = (int)rintf(ab[i]/(act[1]*sf)); return; }
    i -= 196;
    if (i < 3072){ float sf = mx[4]/127.0f; iws[WS_BF1+i] = (int)rintf(f1b[i]/(act[4]*sf)); return; }
    i -= 3072;
    if (i < 768){ float sf = mx[5]/127.0f; iws[WS_BF2+i] = (int)rintf(f2b[i]/(act[5]*sf)); return; }
}

// norm1 + quant_act1 -> q1T CM (per-batch, rows=d 768, K=n 256) + x8 row-major.
__global__ __launch_bounds__(256) void k_stage1(const float* __restrict__ x,
                                                const char* __restrict__ wsc,
                                                char* __restrict__ ws,
                                                const float* __restrict__ act){
    __shared__ i8 T[64][68];
    const float* fws = (const float*)wsc;
    int b = blockIdx.z, n0 = blockIdx.y*64, d0 = blockIdx.x*64;
    int t = threadIdx.x;
    float a0 = act[0];
    float w1sf = fws[WS_MAX+0]/127.0f;
    float r1 = (a0*w1sf)/act[1];
    int dl = (t & 15) * 4;
    int d  = d0 + dl;
    float4 wv = *(const float4*)(fws + WS_W1F + d);
    float4 bv = *(const float4*)(fws + WS_B1F + d);
    i8* x8 = (i8*)(ws + OFF_X8);
    #pragma unroll
    for (int pass = 0; pass < 4; pass++){
        int nl = (t >> 4) + pass*16;
        int n  = n0 + nl;
        i8 q[4] = {0,0,0,0};
        if (n < 196){
            float4 xv = *(const float4*)(x + ((size_t)b*196 + n)*768 + d);
            float i0 = rintf(xv.x/a0), i1 = rintf(xv.y/a0);
            float i2 = rintf(xv.z/a0), i3 = rintf(xv.w/a0);
            *(char4*)(x8 + ((size_t)b*196 + n)*768 + d) =
                make_char4((i8)(int)i0,(i8)(int)i1,(i8)(int)i2,(i8)(int)i3);
            float o0 = rintf(i0*wv.x + bv.x);
            float o1 = rintf(i1*wv.y + bv.y);
            float o2 = rintf(i2*wv.z + bv.z);
            float o3 = rintf(i3*wv.w + bv.w);
            q[0] = (i8)(int)clamp8(rintf(o0*r1));
            q[1] = (i8)(int)clamp8(rintf(o1*r1));
            q[2] = (i8)(int)clamp8(rintf(o2*r1));
            q[3] = (i8)(int)clamp8(rintf(o3*r1));
        }
        T[dl+0][nl] = q[0]; T[dl+1][nl] = q[1];
        T[dl+2][nl] = q[2]; T[dl+3][nl] = q[3];
    }
    __syncthreads();
    i8* q1T = (i8*)(ws + OFF_Q1T) + (size_t)b*196608;
    #pragma unroll
    for (int e = 0; e < 4; e++){
        int id = t + e*256;
        int row = id >> 4, c = (id & 15) * 4;   // d-row local, n-col local
        int dd = d0 + row;
        int v = *(const int*)&T[row][c];
        size_t dst = (((size_t)(dd>>7)*4 + blockIdx.y)<<13) + ((size_t)(c>>4)<<11)
                     + ((dd&127)<<4) + (c&15);
        *(int*)(q1T + dst) = v;
    }
}

// CM double-buffered int8 GEMM, 256 threads: 128x128 tile, wave tile 64x64,
// 16x16x64 fragments. Used by attn (only 4 iters; pipeline depth not worth it).
__device__ __forceinline__ void gemm_cm_256(const i8* __restrict__ gA, const i8* __restrict__ gB,
                                            int iters, int4v acc[4][4], i8* As, i8* Bs, int t){
    int lane = t & 63;
    int wm = (t>>6)&1, wn = t>>7;
    int lo = t*16;
    async16(gA + lo,        As + lo);
    async16(gA + 4096 + lo, As + 4096 + lo);
    async16(gB + lo,        Bs + lo);
    async16(gB + 4096 + lo, Bs + 4096 + lo);
    int arow = (lane>>4)*2048 + (wm*64 + (lane&15))*16;
    int brow = (lane>>4)*2048 + (wn*64 + (lane&15))*16;
    for (int i = 0; i < iters; i++){
        __syncthreads();
        if (i+1 < iters){
            int nb = ((i+1)&1) << 13;
            size_t kb = (size_t)(i+1) << 13;
            async16(gA + kb + lo,        As + nb + lo);
            async16(gA + kb + 4096 + lo, As + nb + 4096 + lo);
            async16(gB + kb + lo,        Bs + nb + lo);
            async16(gB + kb + 4096 + lo, Bs + nb + 4096 + lo);
        }
        int cb = (i&1) << 13;
        int4v a[4], bb[4];
        #pragma unroll
        for (int mt = 0; mt < 4; mt++)
            a[mt] = *(const int4v*)(As + cb + arow + mt*256);
        #pragma unroll
        for (int nt = 0; nt < 4; nt++)
            bb[nt] = *(const int4v*)(Bs + cb + brow + nt*256);
        #pragma unroll
        for (int mt = 0; mt < 4; mt++)
            #pragma unroll
            for (int nt = 0; nt < 4; nt++)
                acc[mt][nt] = __builtin_amdgcn_mfma_i32_16x16x64_i8(a[mt], bb[nt], acc[mt][nt], 0,0,0);
    }
}

// CM int8 GEMM, 256 threads, 128x128 tile, wave tile 64x64, 32x32x32 MFMA,
// TRIPLE-buffered with counted vmcnt (T4): stage(i) waited with vmcnt(4),
// stage(i+1) in flight across the barrier, stage(i+2) issued after it.
// NEW: s_setprio(1) around the MFMA cluster (T5) — with 2-3 INDEPENDENT
// blocks resident per CU (not barrier-synced with each other), MFMA-phase
// waves preempt stage/ds_read-phase waves of sibling blocks (attn-m191
// regime, not the lockstep-null m190 regime).
__device__ __forceinline__ void gemm32_cm_pipe(const i8* __restrict__ gA, const i8* __restrict__ gB,
                                               int iters, int16v acc[2][2], i8* lds, int t){
    int lane = t & 63;
    int wm = (t>>6)&1, wn = t>>7;
    int lo = t*16;
    auto stage = [&](int s, int buf){
        size_t kb = (size_t)s << 13;
        i8* L = lds + buf*16384;
        async16(gA + kb + lo,        L + lo);
        async16(gA + kb + 4096 + lo, L + 4096 + lo);
        async16(gB + kb + lo,        L + 8192 + lo);
        async16(gB + kb + 4096 + lo, L + 12288 + lo);
    };
    stage(0, 0);
    if (iters > 1) stage(1, 1);
    int arow = (lane>>5)*2048 + (wm*64 + (lane&31))*16;
    int brow = 8192 + (lane>>5)*2048 + (wn*64 + (lane&31))*16;
    int buf = 0;
    for (int i = 0; i < iters; i++){
        if (i+1 < iters) asm volatile("s_waitcnt vmcnt(4)" ::: "memory");
        else             asm volatile("s_waitcnt vmcnt(0)" ::: "memory");
        __builtin_amdgcn_s_barrier();
        __builtin_amdgcn_sched_barrier(0);
        if (i+2 < iters){
            int b2 = buf + 2; if (b2 >= 3) b2 -= 3;
            stage(i+2, b2);
        }
        const i8* L = lds + buf*16384;
        int4v a[2][2], bb[2][2];   // [kk][mt/nt]
        #pragma unroll
        for (int kk = 0; kk < 2; kk++){
            #pragma unroll
            for (int mt = 0; mt < 2; mt++){
                a[kk][mt]  = *(const int4v*)(L + kk*4096 + arow + mt*512);
                bb[kk][mt] = *(const int4v*)(L + kk*4096 + brow + mt*512);
            }
        }
        __builtin_amdgcn_s_setprio(1);
        #pragma unroll
        for (int mt = 0; mt < 2; mt++)
            #pragma unroll
            for (int nt = 0; nt < 2; nt++)
                #pragma unroll
                for (int kk = 0; kk < 2; kk++)
                    acc[mt][nt] = __builtin_amdgcn_mfma_i32_32x32x32_i8(a[kk][mt], bb[kk][nt], acc[mt][nt], 0,0,0);
        __builtin_amdgcn_s_setprio(0);
        buf++; if (buf == 3) buf = 0;
    }
}

// attn (4 waves): CM operands; epilogue -> x2 row-major, q3 CM. (R4 version.)
__global__ __launch_bounds__(256) void k_attn(const char* __restrict__ ws,
                                              const float* __restrict__ act){
    __shared__ char smem[32768];
    const float* fws = (const float*)ws;
    const int*   iws = (const int*)ws;
    int b = blockIdx.z;
    int m0 = blockIdx.x*128, n0 = blockIdx.y*128;
    const i8* gA = (const i8*)(ws + OFF_WA)  + ((size_t)(m0>>7))*32768;
    const i8* gB = (const i8*)(ws + OFF_Q1T) + (size_t)b*196608 + ((size_t)(n0>>7))*32768;
    const i8* x8 = (const i8*)(ws + OFF_X8);
    i8* x2  = (i8*)(ws + OFF_X2);
    i8* q3  = (i8*)(ws + OFF_Q3);
    int t = threadIdx.x, lane = t & 63;
    int wm = (t>>6)&1, wn = t>>7;
    int4v acc[4][4]; int4v zz = {0,0,0,0};
    #pragma unroll
    for (int mt=0;mt<4;mt++) for (int nt=0;nt<4;nt++) acc[mt][nt] = zz;
    gemm_cm_256(gA, gB, 4, acc, (i8*)smem, (i8*)smem+16384, t);

    float a1=act[1], a2=act[2], a3=act[3], a4=act[4];
    float wasf = fws[WS_MAX+1]/127.0f; float r2  = (a1*wasf)/a2;
    float g1sf = fws[WS_MAX+2]/127.0f; float r3a = (a2*g1sf)/a3; float r3b = act[0]/a3;
    float w2sf = fws[WS_MAX+3]/127.0f; float r4  = (a3*w2sf)/a4;
    float g1v[4], w2v[4], b2v[4];
    #pragma unroll
    for (int nt=0;nt<4;nt++){
        int d = n0 + wn*64 + nt*16 + (lane&15);
        g1v[nt] = fws[WS_G1F + d]; w2v[nt] = fws[WS_W2F + d]; b2v[nt] = fws[WS_B2F + d];
    }
    __syncthreads();
    i8* Xs = (i8*)smem;
    i8* Qs = (i8*)smem + 16384;
    #pragma unroll
    for (int mt=0;mt<4;mt++){
        #pragma unroll
        for (int r=0;r<4;r++){
            int ml = wm*64 + mt*16 + (lane>>4)*4 + r;
            int o  = m0 + ml;
            int ba = iws[WS_BA + o];
            #pragma unroll
            for (int nt=0;nt<4;nt++){
                int nl = wn*64 + nt*16 + (lane&15);
                int d  = n0 + nl;
                float s2 = (float)(acc[mt][nt][r] + ba);
                float q2 = clamp8(rintf(s2*r2));
                float o3v = q2*g1v[nt];
                float idi = (o < 196) ? (float)x8[((size_t)b*196 + o)*768 + d] : 0.f;
                float tt = rintf(o3v*r3a) + rintf(idi*r3b);
                tt = clamp8(tt);
                float o4 = tt*w2v[nt] + b2v[nt];
                float qr = clamp8(rintf(o4*r4));
                Xs[ml*128 + nl] = (i8)(int)tt;
                Qs[ml*128 + nl] = (i8)(int)qr;
            }
        }
    }
    __syncthreads();
    #pragma unroll
    for (int e=0;e<4;e++){
        int id = t + e*256;
        int row = id>>3, c = id&7;
        int o = m0 + row;
        if (o < 196){
            int rg = b*196 + o;
            size_t g = (size_t)rg*768 + n0 + c*16;
            *(int4v*)(x2 + g) = *(const int4v*)(Xs + row*128 + c*16);
            size_t dst = (((size_t)(rg>>7)*12 + (n0>>6) + (c>>2))<<13)
                         + ((size_t)(c&3)<<11) + ((rg&127)<<4);
            *(int4v*)(q3 + dst) = *(const int4v*)(Qs + row*128 + c*16);
        }
    }
}

// fc1: q3(CM) x fc1(CM) -> relu -> quant -> q4(CM).
// 256x128 tile, 4 waves, wave tile 128x64 (4mt x 2nt), BK=64,
// double-buffered 2x24KB LDS, stage-after-barrier + vmcnt(0) cadence.
// (R9 version — proven.)
__global__ __launch_bounds__(256,2) void k_fc1(const char* __restrict__ ws, const float* __restrict__ act){
    __shared__ char smem[49152];
    const float* fws = (const float*)ws;
    const int*   iws = (const int*)ws;
    int orig = blockIdx.x;
    int wg = (orig & 7) * 147 + (orig >> 3);
    int bx = wg / 24;          // 256-row block 0..48
    int by = wg % 24;          // 128-col block 0..23
    int n0 = by*128;
    const i8* gA = (const i8*)(ws+OFF_Q3)  + (size_t)bx*2*98304;   // 98304 = 12 kblk * 8KB
    const i8* gB = (const i8*)(ws+OFF_FC1) + (size_t)by*98304;
    const int* bias = iws + WS_BF1;
    i8* q4 = (i8*)(ws+OFF_Q4);
    int t = threadIdx.x, lane = t & 63;
    int wm = (t>>6)&1, wn = t>>7;
    int lo = t*16;
    int16v acc[4][2];
    int16v zz = {0,0,0,0,0,0,0,0,0,0,0,0,0,0,0,0};
    #pragma unroll
    for (int mt=0;mt<4;mt++) for (int nt=0;nt<2;nt++) acc[mt][nt] = zz;
    auto stage = [&](int s, int buf){
        size_t kb = (size_t)s << 13;
        i8* L = (i8*)smem + buf*24576;
        async16(gA + kb + lo,                 L + lo);
        async16(gA + kb + 4096 + lo,          L + 4096 + lo);
        async16(gA + 98304 + kb + lo,         L + 8192 + lo);
        async16(gA + 98304 + kb + 4096 + lo,  L + 12288 + lo);
        async16(gB + kb + lo,                 L + 16384 + lo);
        async16(gB + kb + 4096 + lo,          L + 20480 + lo);
    };
    stage(0, 0);
    int arow = wm*8192  + (lane>>5)*2048 + (lane&31)*16;             // + kk*4096 + mt*512
    int brow = 16384 + (lane>>5)*2048 + (wn*64 + (lane&31))*16;      // + kk*4096 + nt*512
    for (int i = 0; i < 12; i++){
        asm volatile("s_waitcnt vmcnt(0)" ::: "memory");
        __builtin_amdgcn_s_barrier();
        __builtin_amdgcn_sched_barrier(0);
        if (i+1 < 12) stage(i+1, (i+1)&1);
        const i8* L = (const i8*)smem + (i&1)*24576;
        #pragma unroll
        for (int kk = 0; kk < 2; kk++){
            int4v a[4], bb[2];
            #pragma unroll
            for (int mt = 0; mt < 4; mt++)
                a[mt] = *(const int4v*)(L + kk*4096 + arow + mt*512);
            #pragma unroll
            for (int nt = 0; nt < 2; nt++)
                bb[nt] = *(const int4v*)(L + kk*4096 + brow + nt*512);
            #pragma unroll
            for (int mt = 0; mt < 4; mt++)
                #pragma unroll
                for (int nt = 0; nt < 2; nt++)
                    acc[mt][nt] = __builtin_amdgcn_mfma_i32_32x32x32_i8(a[mt], bb[nt], acc[mt][nt], 0,0,0);
        }
    }
    float wsf = fws[WS_MAX+4]/127.0f;
    float r5 = (act[4]*wsf)/act[5];
    int bcol[2];
    #pragma unroll
    for (int nt=0;nt<2;nt++) bcol[nt] = bias[n0 + wn*64 + nt*32 + (lane&31)];
    __syncthreads();           // all waves done reading LDS before reuse as Cs
    i8* Cs = (i8*)smem;        // 256x128 = 32KB
    #pragma unroll
    for (int mt=0;mt<4;mt++){
        #pragma unroll
        for (int nt=0;nt<2;nt++){
            int nl = wn*64 + nt*32 + (lane&31);
            #pragma unroll
            for (int r=0;r<16;r++){
                int s = acc[mt][nt][r] + bcol[nt];
                if (s < 0) s = 0;
                float q = clamp8(rintf((float)s * r5));
                // 32x32 C/D: col=lane&31, row=(r&3)+8*(r>>2)+4*(lane>>5)
                int ml = wm*128 + mt*32 + 4*(lane>>5) + (r&3) + 8*(r>>2);
                Cs[ml*128 + nl] = (i8)(int)q;
            }
        }
    }
    __syncthreads();
    #pragma unroll
    for (int e=0;e<8;e++){
        int id = t + e*256;
        int row = id>>3, c = id&7;      // row 0..255, c 0..7
        size_t dst = (((size_t)(bx*2 + (row>>7))*48 + (n0>>6) + (c>>2))<<13)
                     + ((size_t)(c&3)<<11) + ((size_t)(row&127)<<4);
        *(int4v*)(q4 + dst) = *(const int4v*)(Cs + row*128 + c*16);
    }
}

// fc2: q4(CM) x fc2(CM) -> quant -> gamma2 -> +identity -> final quant -> fp32.
// R9 version restored: 128x128 tile, 256 threads, triple-buffer counted-vmcnt
// pipe (+ new T5 setprio inside) + m204 bijective XCD remap, grid 588.
__global__ __launch_bounds__(256,3) void k_fc2(const char* __restrict__ ws, const float* __restrict__ act,
                                               float* __restrict__ out){
    __shared__ char smem[49152];
    const float* fws = (const float*)ws;
    const int*   iws = (const int*)ws;
    int orig = blockIdx.x;
    int xcd = orig & 7, lid = orig >> 3;
    int wg = (xcd < 4 ? xcd*74 : 296 + (xcd-4)*73) + lid;
    int bx = wg / 6;           // M row-block 0..97
    int by = wg % 6;           // N col-block 0..5
    int m0 = bx*128, n0 = by*128;
    const i8* gA = (const i8*)(ws+OFF_Q4)  + ((size_t)bx)*48*8192;
    const i8* gB = (const i8*)(ws+OFF_FC2) + ((size_t)by)*48*8192;
    const int* bias = iws + WS_BF2;
    const float* g2f = fws + WS_G2F;
    const i8* x2 = (const i8*)(ws+OFF_X2);
    int t = threadIdx.x, lane = t & 63;
    int wm = (t>>6)&1, wn = t>>7;
    int16v acc[2][2];
    int16v zz = {0,0,0,0,0,0,0,0,0,0,0,0,0,0,0,0};
    #pragma unroll
    for (int mt=0;mt<2;mt++) for (int nt=0;nt<2;nt++) acc[mt][nt] = zz;
    gemm32_cm_pipe(gA, gB, 48, acc, (i8*)smem, t);
    float a3=act[3], a5=act[5], a6=act[6], a7=act[7];
    float wsf  = fws[WS_MAX+5]/127.0f; float r6  = (a5*wsf)/a6;
    float g2sf = fws[WS_MAX+6]/127.0f; float r7a = (a6*g2sf)/a7; float r7b = a3/a7;
    int bcol[2]; float g2v[2];
    #pragma unroll
    for (int nt=0;nt<2;nt++){
        int nc = n0 + wn*64 + nt*32 + (lane&31);
        bcol[nt] = bias[nc]; g2v[nt] = g2f[nc];
    }
    #pragma unroll
    for (int mt=0;mt<2;mt++){
        #pragma unroll
        for (int nt=0;nt<2;nt++){
            int nc = n0 + wn*64 + nt*32 + (lane&31);
            #pragma unroll
            for (int r=0;r<16;r++){
                // 32x32 C/D: col=lane&31, row=(r&3)+8*(r>>2)+4*(lane>>5)
                int ml = wm*64 + mt*32 + 4*(lane>>5) + (r&3) + 8*(r>>2);
                size_t gi = (size_t)(m0+ml)*768 + nc;
                int s = acc[mt][nt][r] + bcol[nt];
                float q6 = clamp8(rintf((float)s*r6));
                float o7 = q6*g2v[nt];
                float idi = (float)x2[gi];
                float tt = rintf(o7*r7a) + rintf(idi*r7b);
                tt = clamp8(tt);
                out[gi] = tt*a7;
            }
        }
    }
}

extern "C" void kernel_launch(void* const* d_in, const int* in_sizes, int n_in,
                              void* d_out, int out_size, void* d_ws, size_t ws_size,
                              hipStream_t stream){
    const float* x   = (const float*)d_in[0];
    const float* n1w = (const float*)d_in[1];
    const float* n1b = (const float*)d_in[2];
    const float* aw  = (const float*)d_in[3];
    const float* ab  = (const float*)d_in[4];
    const float* g1w = (const float*)d_in[5];
    const float* n2w = (const float*)d_in[6];
    const float* n2b = (const float*)d_in[7];
    const float* f1w = (const float*)d_in[8];
    const float* f1b = (const float*)d_in[9];
    const float* f2w = (const float*)d_in[10];
    const float* f2b = (const float*)d_in[11];
    const float* g2w = (const float*)d_in[12];
    const float* act = (const float*)d_in[13];
    char* ws = (char*)d_ws;
    float* out = (float*)d_out;

    k_init<<<16,256,0,stream>>>(ws, act, out + (size_t)B_*N_*D_);
    k_maxabs<<<dim3(120,7),256,0,stream>>>(n1w, aw, g1w, n2w, f1w, f2w, g2w, (float*)ws);
    long qwThreads = 2L*589824 + 38416 + 768L*6 + 196 + 3072 + 768;
    k_qweights<<<(int)((qwThreads+255)/256),256,0,stream>>>(n1w,n1b,aw,ab,g1w,n2w,n2b,
                                                            f1w,f1b,f2w,f2b,g2w,act,ws);
    k_stage1<<<dim3(12,4,64),256,0,stream>>>(x, ws, ws, act);
    k_attn<<<dim3(2,6,64),256,0,stream>>>(ws, act);
    k_fc1<<<1176,256,0,stream>>>(ws, act);
    k_fc2<<<588,256,0,stream>>>(ws, act, out);
}

// Round 13
// 245.316 us; speedup vs baseline: 1.0597x; 1.0514x over previous
//
#include <hip/hip_runtime.h>

#define B_ 64
#define N_ 196
#define D_ 768
#define H_ 3072
#define M_ (B_*N_)   // 12544
#define NP 256       // padded token count for attn GEMM K / M

typedef int int4v  __attribute__((ext_vector_type(4)));
typedef int int16v __attribute__((ext_vector_type(16)));
typedef signed char i8;

// ---- workspace layout ----
#define WS_MAX 0                 // float[8]: 0 n1w,1 attn,2 g1,3 n2,4 fc1,5 fc2,6 g2
#define WS_W1F 16
#define WS_B1F (16+768)
#define WS_G1F (16+768*2)
#define WS_W2F (16+768*3)
#define WS_B2F (16+768*4)
#define WS_G2F (16+768*5)
#define WS_BA  (16+768*6)        // int[256]
#define WS_BF1 (WS_BA+256)       // int[3072]
#define WS_BF2 (WS_BF1+3072)     // int[768]
// byte offsets. GEMM operands stored CHUNK-MAJOR (CM):
//   [rblk=r/128][kblk=k/64][ksub=(k%64)/16][row=r%128][16B]
// -> staging is a linear 8KB copy; fragment ds_read phases are contiguous.
#define OFF_WA   40960ull                      // CM, 256 rows, K=256 (zero-padded)
#define OFF_FC1  (OFF_WA+65536ull)             // CM, 3072 rows, K=768
#define OFF_FC2  (OFF_FC1+2359296ull)          // CM, 768 rows, K=3072
#define OFF_X2   (OFF_FC2+2359296ull)          // i8[12544][768] row-major
#define OFF_Q3   (OFF_X2+9633792ull)           // CM, 12544 rows, K=768
#define OFF_Q4   (OFF_Q3+9633792ull)           // CM, 12544 rows, K=3072
// q1T (CM, per-batch 768 rows x K=256) and x8 alias the q4 region
#define OFF_Q1T  OFF_Q4                        // 64 x 196608 B
#define OFF_X8   (OFF_Q4+12582912ull)          // i8[12544][768] row-major rint(x/a0)

__device__ __forceinline__ float clamp8(float v){ return fminf(fmaxf(v,-128.f),127.f); }

// async global->LDS, 16B per lane. lds dest = wave-uniform base + lane*16;
// global src is per-lane.
__device__ __forceinline__ void async16(const void* g, void* l){
    __builtin_amdgcn_global_load_lds((const __attribute__((address_space(1))) void*)g,
                                     (__attribute__((address_space(3))) void*)l, 16, 0, 0);
}

__global__ void k_init(char* ws, const float* __restrict__ act, float* out_tail){
    int id = blockIdx.x*256 + threadIdx.x;
    if (blockIdx.x == 0){
        float* f = (float*)ws;
        if (threadIdx.x < 8) f[WS_MAX+threadIdx.x] = 0.f;
        if (threadIdx.x == 8) *out_tail = act[7];
    }
    if (id < 4096){ int4v z = {0,0,0,0}; ((int4v*)(ws+OFF_WA))[id] = z; }
}

__global__ void k_maxabs(const float* __restrict__ p0, const float* __restrict__ p1,
                         const float* __restrict__ p2, const float* __restrict__ p3,
                         const float* __restrict__ p4, const float* __restrict__ p5,
                         const float* __restrict__ p6, float* wsmax){
    const float* ps[7] = {p0,p1,p2,p3,p4,p5,p6};
    const int    n4s[7] = {192, 9604, 192, 192, 589824, 589824, 192};
    int tid = blockIdx.y;
    const float4* p = (const float4*)ps[tid]; int n4 = n4s[tid];
    float m = 0.f;
    for (int i = blockIdx.x*blockDim.x + threadIdx.x; i < n4; i += gridDim.x*blockDim.x){
        float4 v = p[i];
        m = fmaxf(m, fmaxf(fmaxf(fabsf(v.x),fabsf(v.y)), fmaxf(fabsf(v.z),fabsf(v.w))));
    }
    #pragma unroll
    for (int off = 32; off; off >>= 1) m = fmaxf(m, __shfl_down(m, off, 64));
    __shared__ float red[4];
    int lane = threadIdx.x & 63, wv = threadIdx.x >> 6;
    if (lane == 0) red[wv] = m;
    __syncthreads();
    if (threadIdx.x == 0){
        float mm = red[0];
        for (int w = 1; w < (int)blockDim.x/64; w++) mm = fmaxf(mm, red[w]);
        atomicMax((unsigned*)&wsmax[tid], __float_as_uint(mm));
    }
}

// chunk-major offset for row o, k; KC = K/64
__device__ __forceinline__ size_t cm_off(int o, int k, int KC){
    return (((size_t)(o>>7)*KC + (k>>6))<<13) + (((k>>4)&3)<<11) + ((o&127)<<4) + (k&15);
}

// weight quantization. fc1/fc2 branches: 16 k-bytes per thread (4 float4
// loads -> ONE 16B CM store) instead of 4 bytes (4x fewer threads, 16B
// stores replace scattered 4B stores).
__global__ void k_qweights(const float* __restrict__ n1w, const float* __restrict__ n1b,
                           const float* __restrict__ aw,  const float* __restrict__ ab,
                           const float* __restrict__ g1w, const float* __restrict__ n2w,
                           const float* __restrict__ n2b, const float* __restrict__ f1w,
                           const float* __restrict__ f1b, const float* __restrict__ f2w,
                           const float* __restrict__ f2b, const float* __restrict__ g2w,
                           const float* __restrict__ act, char* ws){
    float* fws = (float*)ws;
    int*   iws = (int*)ws;
    const float* mx = fws + WS_MAX;
    long i = (long)blockIdx.x*blockDim.x + threadIdx.x;
    const long F16 = 147456;
    if (i < F16){ float sf = mx[4]/127.0f;
        int o = (int)(i/48), kq = (int)(i%48)*16;
        const float4* p = (const float4*)f1w + (((size_t)o*768 + kq) >> 2);
        int4v r;
        #pragma unroll
        for (int j = 0; j < 4; j++){
            float4 v = p[j];
            unsigned b0 = (unsigned)(unsigned char)(i8)(int)fminf(fmaxf(rintf(v.x/sf),-128.f),127.f);
            unsigned b1 = (unsigned)(unsigned char)(i8)(int)fminf(fmaxf(rintf(v.y/sf),-128.f),127.f);
            unsigned b2 = (unsigned)(unsigned char)(i8)(int)fminf(fmaxf(rintf(v.z/sf),-128.f),127.f);
            unsigned b3 = (unsigned)(unsigned char)(i8)(int)fminf(fmaxf(rintf(v.w/sf),-128.f),127.f);
            r[j] = (int)(b0 | (b1<<8) | (b2<<16) | (b3<<24));
        }
        *(int4v*)(ws + OFF_FC1 + cm_off(o, kq, 12)) = r;
        return; }
    i -= F16;
    if (i < F16){ float sf = mx[5]/127.0f;
        int o = (int)(i/192), kq = (int)(i%192)*16;
        const float4* p = (const float4*)f2w + (((size_t)o*3072 + kq) >> 2);
        int4v r;
        #pragma unroll
        for (int j = 0; j < 4; j++){
            float4 v = p[j];
            unsigned b0 = (unsigned)(unsigned char)(i8)(int)fminf(fmaxf(rintf(v.x/sf),-128.f),127.f);
            unsigned b1 = (unsigned)(unsigned char)(i8)(int)fminf(fmaxf(rintf(v.y/sf),-128.f),127.f);
            unsigned b2 = (unsigned)(unsigned char)(i8)(int)fminf(fmaxf(rintf(v.z/sf),-128.f),127.f);
            unsigned b3 = (unsigned)(unsigned char)(i8)(int)fminf(fmaxf(rintf(v.w/sf),-128.f),127.f);
            r[j] = (int)(b0 | (b1<<8) | (b2<<16) | (b3<<24));
        }
        *(int4v*)(ws + OFF_FC2 + cm_off(o, kq, 48)) = r;
        return; }
    i -= F16;
    if (i < 38416){ float sf = mx[1]/127.0f;
        int o = (int)(i/196), k = (int)(i%196);
        ((i8*)(ws+OFF_WA))[cm_off(o, k, 4)] =
            (i8)(int)fminf(fmaxf(rintf(aw[i]/sf),-128.f),127.f); return; }
    i -= 38416;
    if (i < 768){ float sf = mx[0]/127.0f; fws[WS_W1F+i] = rintf(n1w[i]/sf); return; }
    i -= 768;
    if (i < 768){ float sf = mx[0]/127.0f; fws[WS_B1F+i] = rintf(n1b[i]/(act[0]*sf)); return; }
    i -= 768;
    if (i < 768){ float sf = mx[2]/127.0f; fws[WS_G1F+i] = rintf(g1w[i]/sf); return; }
    i -= 768;
    if (i < 768){ float sf = mx[3]/127.0f; fws[WS_W2F+i] = rintf(n2w[i]/sf); return; }
    i -= 768;
    if (i < 768){ float sf = mx[3]/127.0f; fws[WS_B2F+i] = rintf(n2b[i]/(act[3]*sf)); return; }
    i -= 768;
    if (i < 768){ float sf = mx[6]/127.0f; fws[WS_G2F+i] = rintf(g2w[i]/sf); return; }
    i -= 768;
    if (i < 196){ float sf = mx[1]/127.0f; iws[WS_BA+i] = (int)rintf(ab[i]/(act[1]*sf)); return; }
    i -= 196;
    if (i < 3072){ float sf = mx[4]/127.0f; iws[WS_BF1+i] = (int)rintf(f1b[i]/(act[4]*sf)); return; }
    i -= 3072;
    if (i < 768){ float sf = mx[5]/127.0f; iws[WS_BF2+i] = (int)rintf(f2b[i]/(act[5]*sf)); return; }
}

// norm1 + quant_act1 -> q1T CM (per-batch, rows=d 768, K=n 256) + x8 row-major.
// q1T write vectorized: one int4v (16B CM cell) per thread; T padded to 80
// stride for 16B-aligned LDS reads.
__global__ __launch_bounds__(256) void k_stage1(const float* __restrict__ x,
                                                const char* __restrict__ wsc,
                                                char* __restrict__ ws,
                                                const float* __restrict__ act){
    __shared__ i8 T[64][80];
    const float* fws = (const float*)wsc;
    int b = blockIdx.z, n0 = blockIdx.y*64, d0 = blockIdx.x*64;
    int t = threadIdx.x;
    float a0 = act[0];
    float w1sf = fws[WS_MAX+0]/127.0f;
    float r1 = (a0*w1sf)/act[1];
    int dl = (t & 15) * 4;
    int d  = d0 + dl;
    float4 wv = *(const float4*)(fws + WS_W1F + d);
    float4 bv = *(const float4*)(fws + WS_B1F + d);
    i8* x8 = (i8*)(ws + OFF_X8);
    #pragma unroll
    for (int pass = 0; pass < 4; pass++){
        int nl = (t >> 4) + pass*16;
        int n  = n0 + nl;
        i8 q[4] = {0,0,0,0};
        if (n < 196){
            float4 xv = *(const float4*)(x + ((size_t)b*196 + n)*768 + d);
            float i0 = rintf(xv.x/a0), i1 = rintf(xv.y/a0);
            float i2 = rintf(xv.z/a0), i3 = rintf(xv.w/a0);
            *(char4*)(x8 + ((size_t)b*196 + n)*768 + d) =
                make_char4((i8)(int)i0,(i8)(int)i1,(i8)(int)i2,(i8)(int)i3);
            float o0 = rintf(i0*wv.x + bv.x);
            float o1 = rintf(i1*wv.y + bv.y);
            float o2 = rintf(i2*wv.z + bv.z);
            float o3 = rintf(i3*wv.w + bv.w);
            q[0] = (i8)(int)clamp8(rintf(o0*r1));
            q[1] = (i8)(int)clamp8(rintf(o1*r1));
            q[2] = (i8)(int)clamp8(rintf(o2*r1));
            q[3] = (i8)(int)clamp8(rintf(o3*r1));
        }
        T[dl+0][nl] = q[0]; T[dl+1][nl] = q[1];
        T[dl+2][nl] = q[2]; T[dl+3][nl] = q[3];
    }
    __syncthreads();
    i8* q1T = (i8*)(ws + OFF_Q1T) + (size_t)b*196608;
    {
        int row = t >> 2;            // d-row local 0..63
        int c   = (t & 3) * 16;      // n-col local 0,16,32,48
        int dd  = d0 + row;
        int4v v = *(const int4v*)&T[row][c];
        size_t dst = (((size_t)(dd>>7)*4 + blockIdx.y)<<13) + ((size_t)(c>>4)<<11)
                     + ((dd&127)<<4);
        *(int4v*)(q1T + dst) = v;
    }
}

// CM double-buffered int8 GEMM, 256 threads: 128x128 tile, wave tile 64x64,
// 16x16x64 fragments. Used by attn (only 4 iters; pipeline depth not worth it).
__device__ __forceinline__ void gemm_cm_256(const i8* __restrict__ gA, const i8* __restrict__ gB,
                                            int iters, int4v acc[4][4], i8* As, i8* Bs, int t){
    int lane = t & 63;
    int wm = (t>>6)&1, wn = t>>7;
    int lo = t*16;
    async16(gA + lo,        As + lo);
    async16(gA + 4096 + lo, As + 4096 + lo);
    async16(gB + lo,        Bs + lo);
    async16(gB + 4096 + lo, Bs + 4096 + lo);
    int arow = (lane>>4)*2048 + (wm*64 + (lane&15))*16;
    int brow = (lane>>4)*2048 + (wn*64 + (lane&15))*16;
    for (int i = 0; i < iters; i++){
        __syncthreads();
        if (i+1 < iters){
            int nb = ((i+1)&1) << 13;
            size_t kb = (size_t)(i+1) << 13;
            async16(gA + kb + lo,        As + nb + lo);
            async16(gA + kb + 4096 + lo, As + nb + 4096 + lo);
            async16(gB + kb + lo,        Bs + nb + lo);
            async16(gB + kb + 4096 + lo, Bs + nb + 4096 + lo);
        }
        int cb = (i&1) << 13;
        int4v a[4], bb[4];
        #pragma unroll
        for (int mt = 0; mt < 4; mt++)
            a[mt] = *(const int4v*)(As + cb + arow + mt*256);
        #pragma unroll
        for (int nt = 0; nt < 4; nt++)
            bb[nt] = *(const int4v*)(Bs + cb + brow + nt*256);
        #pragma unroll
        for (int mt = 0; mt < 4; mt++)
            #pragma unroll
            for (int nt = 0; nt < 4; nt++)
                acc[mt][nt] = __builtin_amdgcn_mfma_i32_16x16x64_i8(a[mt], bb[nt], acc[mt][nt], 0,0,0);
    }
}

// CM int8 GEMM, 256 threads, 128x128 tile, wave tile 64x64, 32x32x32 MFMA,
// TRIPLE-buffered with counted vmcnt (T4). R9 structure (best measured).
__device__ __forceinline__ void gemm32_cm_pipe(const i8* __restrict__ gA, const i8* __restrict__ gB,
                                               int iters, int16v acc[2][2], i8* lds, int t){
    int lane = t & 63;
    int wm = (t>>6)&1, wn = t>>7;
    int lo = t*16;
    auto stage = [&](int s, int buf){
        size_t kb = (size_t)s << 13;
        i8* L = lds + buf*16384;
        async16(gA + kb + lo,        L + lo);
        async16(gA + kb + 4096 + lo, L + 4096 + lo);
        async16(gB + kb + lo,        L + 8192 + lo);
        async16(gB + kb + 4096 + lo, L + 12288 + lo);
    };
    stage(0, 0);
    if (iters > 1) stage(1, 1);
    int arow = (lane>>5)*2048 + (wm*64 + (lane&31))*16;
    int brow = 8192 + (lane>>5)*2048 + (wn*64 + (lane&31))*16;
    int buf = 0;
    for (int i = 0; i < iters; i++){
        if (i+1 < iters) asm volatile("s_waitcnt vmcnt(4)" ::: "memory");
        else             asm volatile("s_waitcnt vmcnt(0)" ::: "memory");
        __builtin_amdgcn_s_barrier();
        __builtin_amdgcn_sched_barrier(0);
        if (i+2 < iters){
            int b2 = buf + 2; if (b2 >= 3) b2 -= 3;
            stage(i+2, b2);
        }
        const i8* L = lds + buf*16384;
        int4v a[2][2], bb[2][2];   // [kk][mt/nt]
        #pragma unroll
        for (int kk = 0; kk < 2; kk++){
            #pragma unroll
            for (int mt = 0; mt < 2; mt++){
                a[kk][mt]  = *(const int4v*)(L + kk*4096 + arow + mt*512);
                bb[kk][mt] = *(const int4v*)(L + kk*4096 + brow + mt*512);
            }
        }
        #pragma unroll
        for (int mt = 0; mt < 2; mt++)
            #pragma unroll
            for (int nt = 0; nt < 2; nt++)
                #pragma unroll
                for (int kk = 0; kk < 2; kk++)
                    acc[mt][nt] = __builtin_amdgcn_mfma_i32_32x32x32_i8(a[kk][mt], bb[kk][nt], acc[mt][nt], 0,0,0);
        buf++; if (buf == 3) buf = 0;
    }
}

// attn (4 waves): CM operands; epilogue -> x2 row-major, q3 CM.
// x8 identity tile (128x128) staged into LDS via global_load_lds (issued
// before the GEMM; drained free at its first barrier). The epilogue's 64
// scalar-byte VMEM gathers per thread become cheap LDS byte reads.
// LDS 48KB; grid 768 needs exactly 3 blocks/CU -> 3x48=144 <= 160KB.
__global__ __launch_bounds__(256) void k_attn(const char* __restrict__ ws,
                                              const float* __restrict__ act){
    __shared__ char smem[49152];
    const float* fws = (const float*)ws;
    const int*   iws = (const int*)ws;
    int b = blockIdx.z;
    int m0 = blockIdx.x*128, n0 = blockIdx.y*128;
    const i8* gA = (const i8*)(ws + OFF_WA)  + ((size_t)(m0>>7))*32768;
    const i8* gB = (const i8*)(ws + OFF_Q1T) + (size_t)b*196608 + ((size_t)(n0>>7))*32768;
    const i8* x8 = (const i8*)(ws + OFF_X8);
    i8* x2  = (i8*)(ws + OFF_X2);
    i8* q3  = (i8*)(ws + OFF_Q3);
    int t = threadIdx.x, lane = t & 63;
    int wm = (t>>6)&1, wn = t>>7;
    // stage x8[m0..m0+127][n0..n0+127] -> Xs8 (rows >=196 skipped, masked at use)
    i8* Xs8 = (i8*)smem + 32768;
    #pragma unroll
    for (int e = 0; e < 4; e++){
        int row = e*32 + (t>>3);
        int o   = m0 + row;
        if (o < 196)
            async16(x8 + ((size_t)b*196 + o)*768 + n0 + (t&7)*16, Xs8 + e*4096 + t*16);
    }
    int4v acc[4][4]; int4v zz = {0,0,0,0};
    #pragma unroll
    for (int mt=0;mt<4;mt++) for (int nt=0;nt<4;nt++) acc[mt][nt] = zz;
    gemm_cm_256(gA, gB, 4, acc, (i8*)smem, (i8*)smem+16384, t);

    float a1=act[1], a2=act[2], a3=act[3], a4=act[4];
    float wasf = fws[WS_MAX+1]/127.0f; float r2  = (a1*wasf)/a2;
    float g1sf = fws[WS_MAX+2]/127.0f; float r3a = (a2*g1sf)/a3; float r3b = act[0]/a3;
    float w2sf = fws[WS_MAX+3]/127.0f; float r4  = (a3*w2sf)/a4;
    float g1v[4], w2v[4], b2v[4];
    #pragma unroll
    for (int nt=0;nt<4;nt++){
        int d = n0 + wn*64 + nt*16 + (lane&15);
        g1v[nt] = fws[WS_G1F + d]; w2v[nt] = fws[WS_W2F + d]; b2v[nt] = fws[WS_B2F + d];
    }
    __syncthreads();
    i8* Xs = (i8*)smem;
    i8* Qs = (i8*)smem + 16384;
    #pragma unroll
    for (int mt=0;mt<4;mt++){
        #pragma unroll
        for (int r=0;r<4;r++){
            int ml = wm*64 + mt*16 + (lane>>4)*4 + r;
            int o  = m0 + ml;
            int ba = iws[WS_BA + o];
            #pragma unroll
            for (int nt=0;nt<4;nt++){
                int nl = wn*64 + nt*16 + (lane&15);
                float s2 = (float)(acc[mt][nt][r] + ba);
                float q2 = clamp8(rintf(s2*r2));
                float o3v = q2*g1v[nt];
                float idi = (o < 196) ? (float)Xs8[ml*128 + nl] : 0.f;
                float tt = rintf(o3v*r3a) + rintf(idi*r3b);
                tt = clamp8(tt);
                float o4 = tt*w2v[nt] + b2v[nt];
                float qr = clamp8(rintf(o4*r4));
                Xs[ml*128 + nl] = (i8)(int)tt;
                Qs[ml*128 + nl] = (i8)(int)qr;
            }
        }
    }
    __syncthreads();
    #pragma unroll
    for (int e=0;e<4;e++){
        int id = t + e*256;
        int row = id>>3, c = id&7;
        int o = m0 + row;
        if (o < 196){
            int rg = b*196 + o;
            size_t g = (size_t)rg*768 + n0 + c*16;
            *(int4v*)(x2 + g) = *(const int4v*)(Xs + row*128 + c*16);
            size_t dst = (((size_t)(rg>>7)*12 + (n0>>6) + (c>>2))<<13)
                         + ((size_t)(c&3)<<11) + ((rg&127)<<4);
            *(int4v*)(q3 + dst) = *(const int4v*)(Qs + row*128 + c*16);
        }
    }
}

// fc1: q3(CM) x fc1(CM) -> relu -> quant -> q4(CM).
// 256x128 tile, 4 waves, wave tile 128x64 (4mt x 2nt), BK=64,
// double-buffered 2x24KB LDS, stage-after-barrier + vmcnt(0) cadence.
// (R9 version — proven.)
__global__ __launch_bounds__(256,2) void k_fc1(const char* __restrict__ ws, const float* __restrict__ act){
    __shared__ char smem[49152];
    const float* fws = (const float*)ws;
    const int*   iws = (const int*)ws;
    int orig = blockIdx.x;
    int wg = (orig & 7) * 147 + (orig >> 3);
    int bx = wg / 24;          // 256-row block 0..48
    int by = wg % 24;          // 128-col block 0..23
    int n0 = by*128;
    const i8* gA = (const i8*)(ws+OFF_Q3)  + (size_t)bx*2*98304;   // 98304 = 12 kblk * 8KB
    const i8* gB = (const i8*)(ws+OFF_FC1) + (size_t)by*98304;
    const int* bias = iws + WS_BF1;
    i8* q4 = (i8*)(ws+OFF_Q4);
    int t = threadIdx.x, lane = t & 63;
    int wm = (t>>6)&1, wn = t>>7;
    int lo = t*16;
    int16v acc[4][2];
    int16v zz = {0,0,0,0,0,0,0,0,0,0,0,0,0,0,0,0};
    #pragma unroll
    for (int mt=0;mt<4;mt++) for (int nt=0;nt<2;nt++) acc[mt][nt] = zz;
    auto stage = [&](int s, int buf){
        size_t kb = (size_t)s << 13;
        i8* L = (i8*)smem + buf*24576;
        async16(gA + kb + lo,                 L + lo);
        async16(gA + kb + 4096 + lo,          L + 4096 + lo);
        async16(gA + 98304 + kb + lo,         L + 8192 + lo);
        async16(gA + 98304 + kb + 4096 + lo,  L + 12288 + lo);
        async16(gB + kb + lo,                 L + 16384 + lo);
        async16(gB + kb + 4096 + lo,          L + 20480 + lo);
    };
    stage(0, 0);
    int arow = wm*8192  + (lane>>5)*2048 + (lane&31)*16;             // + kk*4096 + mt*512
    int brow = 16384 + (lane>>5)*2048 + (wn*64 + (lane&31))*16;      // + kk*4096 + nt*512
    for (int i = 0; i < 12; i++){
        asm volatile("s_waitcnt vmcnt(0)" ::: "memory");
        __builtin_amdgcn_s_barrier();
        __builtin_amdgcn_sched_barrier(0);
        if (i+1 < 12) stage(i+1, (i+1)&1);
        const i8* L = (const i8*)smem + (i&1)*24576;
        #pragma unroll
        for (int kk = 0; kk < 2; kk++){
            int4v a[4], bb[2];
            #pragma unroll
            for (int mt = 0; mt < 4; mt++)
                a[mt] = *(const int4v*)(L + kk*4096 + arow + mt*512);
            #pragma unroll
            for (int nt = 0; nt < 2; nt++)
                bb[nt] = *(const int4v*)(L + kk*4096 + brow + nt*512);
            #pragma unroll
            for (int mt = 0; mt < 4; mt++)
                #pragma unroll
                for (int nt = 0; nt < 2; nt++)
                    acc[mt][nt] = __builtin_amdgcn_mfma_i32_32x32x32_i8(a[mt], bb[nt], acc[mt][nt], 0,0,0);
        }
    }
    float wsf = fws[WS_MAX+4]/127.0f;
    float r5 = (act[4]*wsf)/act[5];
    int bcol[2];
    #pragma unroll
    for (int nt=0;nt<2;nt++) bcol[nt] = bias[n0 + wn*64 + nt*32 + (lane&31)];
    __syncthreads();           // all waves done reading LDS before reuse as Cs
    i8* Cs = (i8*)smem;        // 256x128 = 32KB
    #pragma unroll
    for (int mt=0;mt<4;mt++){
        #pragma unroll
        for (int nt=0;nt<2;nt++){
            int nl = wn*64 + nt*32 + (lane&31);
            #pragma unroll
            for (int r=0;r<16;r++){
                int s = acc[mt][nt][r] + bcol[nt];
                if (s < 0) s = 0;
                float q = clamp8(rintf((float)s * r5));
                // 32x32 C/D: col=lane&31, row=(r&3)+8*(r>>2)+4*(lane>>5)
                int ml = wm*128 + mt*32 + 4*(lane>>5) + (r&3) + 8*(r>>2);
                Cs[ml*128 + nl] = (i8)(int)q;
            }
        }
    }
    __syncthreads();
    #pragma unroll
    for (int e=0;e<8;e++){
        int id = t + e*256;
        int row = id>>3, c = id&7;      // row 0..255, c 0..7
        size_t dst = (((size_t)(bx*2 + (row>>7))*48 + (n0>>6) + (c>>2))<<13)
                     + ((size_t)(c&3)<<11) + ((size_t)(row&127)<<4);
        *(int4v*)(q4 + dst) = *(const int4v*)(Cs + row*128 + c*16);
    }
}

// fc2: q4(CM) x fc2(CM) -> quant -> gamma2 -> +identity -> final quant -> fp32.
// R9 version: 128x128 tile, 256 threads, triple-buffer counted-vmcnt pipe
// + m204 bijective XCD remap, grid 588.
__global__ __launch_bounds__(256,3) void k_fc2(const char* __restrict__ ws, const float* __restrict__ act,
                                               float* __restrict__ out){
    __shared__ char smem[49152];
    const float* fws = (const float*)ws;
    const int*   iws = (const int*)ws;
    int orig = blockIdx.x;
    int xcd = orig & 7, lid = orig >> 3;
    int wg = (xcd < 4 ? xcd*74 : 296 + (xcd-4)*73) + lid;
    int bx = wg / 6;           // M row-block 0..97
    int by = wg % 6;           // N col-block 0..5
    int m0 = bx*128, n0 = by*128;
    const i8* gA = (const i8*)(ws+OFF_Q4)  + ((size_t)bx)*48*8192;
    const i8* gB = (const i8*)(ws+OFF_FC2) + ((size_t)by)*48*8192;
    const int* bias = iws + WS_BF2;
    const float* g2f = fws + WS_G2F;
    const i8* x2 = (const i8*)(ws+OFF_X2);
    int t = threadIdx.x, lane = t & 63;
    int wm = (t>>6)&1, wn = t>>7;
    int16v acc[2][2];
    int16v zz = {0,0,0,0,0,0,0,0,0,0,0,0,0,0,0,0};
    #pragma unroll
    for (int mt=0;mt<2;mt++) for (int nt=0;nt<2;nt++) acc[mt][nt] = zz;
    gemm32_cm_pipe(gA, gB, 48, acc, (i8*)smem, t);
    float a3=act[3], a5=act[5], a6=act[6], a7=act[7];
    float wsf  = fws[WS_MAX+5]/127.0f; float r6  = (a5*wsf)/a6;
    float g2sf = fws[WS_MAX+6]/127.0f; float r7a = (a6*g2sf)/a7; float r7b = a3/a7;
    int bcol[2]; float g2v[2];
    #pragma unroll
    for (int nt=0;nt<2;nt++){
        int nc = n0 + wn*64 + nt*32 + (lane&31);
        bcol[nt] = bias[nc]; g2v[nt] = g2f[nc];
    }
    #pragma unroll
    for (int mt=0;mt<2;mt++){
        #pragma unroll
        for (int nt=0;nt<2;nt++){
            int nc = n0 + wn*64 + nt*32 + (lane&31);
            #pragma unroll
            for (int r=0;r<16;r++){
                // 32x32 C/D: col=lane&31, row=(r&3)+8*(r>>2)+4*(lane>>5)
                int ml = wm*64 + mt*32 + 4*(lane>>5) + (r&3) + 8*(r>>2);
                size_t gi = (size_t)(m0+ml)*768 + nc;
                int s = acc[mt][nt][r] + bcol[nt];
                float q6 = clamp8(rintf((float)s*r6));
                float o7 = q6*g2v[nt];
                float idi = (float)x2[gi];
                float tt = rintf(o7*r7a) + rintf(idi*r7b);
                tt = clamp8(tt);
                out[gi] = tt*a7;
            }
        }
    }
}

extern "C" void kernel_launch(void* const* d_in, const int* in_sizes, int n_in,
                              void* d_out, int out_size, void* d_ws, size_t ws_size,
                              hipStream_t stream){
    const float* x   = (const float*)d_in[0];
    const float* n1w = (const float*)d_in[1];
    const float* n1b = (const float*)d_in[2];
    const float* aw  = (const float*)d_in[3];
    const float* ab  = (const float*)d_in[4];
    const float* g1w = (const float*)d_in[5];
    const float* n2w = (const float*)d_in[6];
    const float* n2b = (const float*)d_in[7];
    const float* f1w = (const float*)d_in[8];
    const float* f1b = (const float*)d_in[9];
    const float* f2w = (const float*)d_in[10];
    const float* f2b = (const float*)d_in[11];
    const float* g2w = (const float*)d_in[12];
    const float* act = (const float*)d_in[13];
    char* ws = (char*)d_ws;
    float* out = (float*)d_out;

    k_init<<<16,256,0,stream>>>(ws, act, out + (size_t)B_*N_*D_);
    k_maxabs<<<dim3(120,7),256,0,stream>>>(n1w, aw, g1w, n2w, f1w, f2w, g2w, (float*)ws);
    long qwThreads = 2L*147456 + 38416 + 768L*6 + 196 + 3072 + 768;
    k_qweights<<<(int)((qwThreads+255)/256),256,0,stream>>>(n1w,n1b,aw,ab,g1w,n2w,n2b,
                                                            f1w,f1b,f2w,f2b,g2w,act,ws);
    k_stage1<<<dim3(12,4,64),256,0,stream>>>(x, ws, ws, act);
    k_attn<<<dim3(2,6,64),256,0,stream>>>(ws, act);
    k_fc1<<<1176,256,0,stream>>>(ws, act);
    k_fc2<<<588,256,0,stream>>>(ws, act, out);
}